// Round 13
// baseline (117.004 us; speedup 1.0000x reference)
//
#include <hip/hip_runtime.h>
#include <hip/hip_bf16.h>

#define B_ 2
#define S_ 2048
#define D_ 1024
#define H_ 16
#define HD_ 64
#define M_ (B_ * S_)   // 4096 tokens

// scale folded into Q at projection time: exp(score/sqrt(HD)) = exp2(qk * SC2L)
#define SC2L 0.18033688011112042f   // 0.125 * log2(e)

typedef __attribute__((ext_vector_type(8))) short short8;
typedef __attribute__((ext_vector_type(4))) float f32x4;
typedef __attribute__((ext_vector_type(16))) float f32x16;
using bf16_t = __hip_bfloat16;

__device__ __forceinline__ float fast_exp2(float x) { return __builtin_amdgcn_exp2f(x); }

__device__ __forceinline__ short f2bfs(float f) {
    __hip_bfloat16 h = __float2bfloat16(f);
    return *reinterpret_cast<short*>(&h);
}

typedef __attribute__((address_space(1))) const unsigned int gl_u32;
typedef __attribute__((address_space(3))) unsigned int lds_u32;

__device__ __forceinline__ void gl_lds16(const bf16_t* g, bf16_t* l) {
    __builtin_amdgcn_global_load_lds((gl_u32*)g, (lds_u32*)l, 16, 0, 0);
}

// XOR-swizzle for [R][64]-bf16 tiles (128 B rows), attn K/V tiles.
__device__ __forceinline__ int swzb(int row, int colbyte) {
    return (row << 7) + (colbyte ^ ((row & 7) << 4));
}

// XOR-swizzle for [R][32]-bf16 tiles (64 B rows, 4 chunks of 16 B), GEMM BK=32.
__device__ __forceinline__ int swz32(int row, int chunk) {
    return (row << 6) + ((chunk ^ ((row >> 1) & 3)) << 4);
}

// ---------- fused prep: 4x W transpose->bf16 (z<4) + x->bf16 (z==4) ----------
__global__ __launch_bounds__(256) void k_prep(const float* __restrict__ x,
                                              const float* __restrict__ W0,
                                              const float* __restrict__ W1,
                                              const float* __restrict__ W2,
                                              const float* __restrict__ W3,
                                              bf16_t* __restrict__ xb,
                                              bf16_t* T0, bf16_t* T1, bf16_t* T2, bf16_t* T3) {
    const int z = blockIdx.z;
    const int tx = threadIdx.x, ty = threadIdx.y;           // (32, 8)
    if (z == 4) {
        const int blk = blockIdx.y * 32 + blockIdx.x;
        const int tid = ty * 32 + tx;
        int i = blk * 4096 + tid * 16;
#pragma unroll
        for (int half = 0; half < 2; ++half) {
            float4 f0 = ((const float4*)(x + i))[0];
            float4 f1 = ((const float4*)(x + i))[1];
            short8 v;
            v[0] = f2bfs(f0.x); v[1] = f2bfs(f0.y); v[2] = f2bfs(f0.z); v[3] = f2bfs(f0.w);
            v[4] = f2bfs(f1.x); v[5] = f2bfs(f1.y); v[6] = f2bfs(f1.z); v[7] = f2bfs(f1.w);
            *(short8*)(xb + i) = v;
            i += 8;
        }
        return;
    }
    __shared__ float tile[32][33];
    const float* W = z == 0 ? W0 : z == 1 ? W1 : z == 2 ? W2 : W3;
    bf16_t* Wt = z == 0 ? T0 : z == 1 ? T1 : z == 2 ? T2 : T3;
    const int n0 = blockIdx.x * 32, k0 = blockIdx.y * 32;
#pragma unroll
    for (int r = 0; r < 4; ++r)
        tile[ty + 8 * r][tx] = W[(size_t)(k0 + ty + 8 * r) * D_ + n0 + tx];
    __syncthreads();
#pragma unroll
    for (int r = 0; r < 4; ++r)
        Wt[(size_t)(n0 + ty + 8 * r) * D_ + k0 + tx] = __float2bfloat16(tile[tx][ty + 8 * r]);
}

// ---------- GEMM helpers: 128x128 tile, BK=32, 4 waves, 3-buf counted-vmcnt ----------
__device__ __forceinline__ void stage_pair32(const bf16_t* __restrict__ Asrc,
                                             const bf16_t* __restrict__ Bsrc,
                                             int k0, int tid,
                                             bf16_t* Ab, bf16_t* Bb) {
#pragma unroll
    for (int c = 0; c < 2; ++c) {
        int idx = c * 256 + tid;          // 0..511 chunk index over [128][4]
        int r = idx >> 2, ch = idx & 3;
        int cs = ch ^ ((r >> 1) & 3);     // pre-swizzled source chunk
        gl_lds16(Asrc + (size_t)r * D_ + k0 + cs * 8, Ab + idx * 8);
        gl_lds16(Bsrc + (size_t)r * D_ + k0 + cs * 8, Bb + idx * 8);
    }
}

__device__ __forceinline__ void gemm_compute32(const bf16_t* Ab, const bf16_t* Bb,
                                               int lane, int wr, int wc, f32x4 acc[4][4]) {
    const char* AbC = (const char*)Ab;
    const char* BbC = (const char*)Bb;
    const int g = lane >> 4;
    short8 af[4], bf[4];
    const int arow = wr * 64 + (lane & 15);
    const int brow = wc * 64 + (lane & 15);
#pragma unroll
    for (int i = 0; i < 4; ++i) af[i] = *(const short8*)(AbC + swz32(arow + i * 16, g));
#pragma unroll
    for (int j = 0; j < 4; ++j) bf[j] = *(const short8*)(BbC + swz32(brow + j * 16, g));
#pragma unroll
    for (int i = 0; i < 4; ++i)
#pragma unroll
        for (int j = 0; j < 4; ++j)
            acc[i][j] = __builtin_amdgcn_mfma_f32_16x16x32_bf16(af[i], bf[j], acc[i][j], 0, 0, 0);
}

// Counted-vmcnt depth-2 K-loop (T3/T4): stage(s+1) stays in flight ACROSS the
// barrier (vmcnt(4) waits only for stage(s)'s 4 loads); stage(s+2) is issued
// after the barrier (safe: all waves' step s-1 ds_reads retired at barrier).
#define GEMM_KLOOP(ASRC, BSRC)                                                   \
    stage_pair32(ASRC, BSRC, 0, tid, Ab[0], Bb[0]);                              \
    stage_pair32(ASRC, BSRC, 32, tid, Ab[1], Bb[1]);                             \
    constexpr int NS = D_ / 32;                                                  \
    _Pragma("unroll 3")                                                          \
    for (int step = 0; step < NS - 1; ++step) {                                  \
        asm volatile("s_waitcnt vmcnt(4)" ::: "memory");                         \
        __builtin_amdgcn_s_barrier();                                            \
        if (step + 2 < NS)                                                       \
            stage_pair32(ASRC, BSRC, (step + 2) * 32, tid,                       \
                         Ab[(step + 2) % 3], Bb[(step + 2) % 3]);                \
        gemm_compute32(Ab[step % 3], Bb[step % 3], lane, wr, wc, acc);           \
    }                                                                            \
    asm volatile("s_waitcnt vmcnt(0)" ::: "memory");                             \
    __builtin_amdgcn_s_barrier();                                                \
    gemm_compute32(Ab[(NS - 1) % 3], Bb[(NS - 1) % 3], lane, wr, wc, acc);

// ---------- fused QKV GEMM: Q (pre-scaled by SC2L), K -> [B,H,S,HD]; V -> [B,H,HD,S] ----------
__global__ __launch_bounds__(256, 4) void k_qkv(const bf16_t* __restrict__ xb,
                                                const bf16_t* __restrict__ Wtq,
                                                const bf16_t* __restrict__ Wtk,
                                                const bf16_t* __restrict__ Wtv,
                                                const float* __restrict__ bq,
                                                const float* __restrict__ bk,
                                                const float* __restrict__ bv,
                                                bf16_t* __restrict__ Qh,
                                                bf16_t* __restrict__ Kh,
                                                bf16_t* __restrict__ Vt) {
    __shared__ __align__(16) bf16_t Ab[3][128 * 32];
    __shared__ __align__(16) bf16_t Bb[3][128 * 32];
    const int p = blockIdx.x;
    const int v0 = (p & 7) * 96 + (p >> 3);   // bijective: 768 = 8*96
    const int sc = v0 % 24;
    const int sel = sc >> 3;
    const bf16_t* Bt = sel == 0 ? Wtq : sel == 1 ? Wtk : Wtv;
    const float* bias = sel == 0 ? bq : sel == 1 ? bk : bv;
    const int col0 = (sc & 7) * 128;
    const int row0 = (v0 / 24) * 128;
    const int tid = threadIdx.x, lane = tid & 63, w = tid >> 6;
    const int wr = w >> 1, wc = w & 1;
    const bf16_t* Asrc = xb + (size_t)row0 * D_;
    const bf16_t* Bsrc = Bt + (size_t)col0 * D_;

    f32x4 acc[4][4];
#pragma unroll
    for (int i = 0; i < 4; ++i)
#pragma unroll
        for (int j = 0; j < 4; ++j) acc[i][j] = (f32x4){0.f, 0.f, 0.f, 0.f};

    GEMM_KLOOP(Asrc, Bsrc)

#pragma unroll
    for (int i = 0; i < 4; ++i)
#pragma unroll
        for (int j = 0; j < 4; ++j)
#pragma unroll
            for (int r = 0; r < 4; ++r) {
                int grow = row0 + wr * 64 + i * 16 + 4 * (lane >> 4) + r;
                int gcol = col0 + wc * 64 + j * 16 + (lane & 15);
                float v = acc[i][j][r] + bias[gcol];
                int b = grow >> 11, s = grow & (S_ - 1);
                int h = gcol >> 6, hd = gcol & (HD_ - 1);
                if (sel == 0)   // fold softmax scale*log2(e) into Q (fp32, pre-round)
                    Qh[(((size_t)b * H_ + h) * S_ + s) * HD_ + hd] = __float2bfloat16(v * SC2L);
                else if (sel == 1)
                    Kh[(((size_t)b * H_ + h) * S_ + s) * HD_ + hd] = __float2bfloat16(v);
                else
                    Vt[(((size_t)b * H_ + h) * HD_ + hd) * S_ + s] = __float2bfloat16(v);
            }
}

// ---------- final projection: d_out[M,D] fp32 = AO[M,D]bf16 * Wto^T + bo ----------
__global__ __launch_bounds__(256, 4) void k_gemm_out(const bf16_t* __restrict__ AO,
                                                     const bf16_t* __restrict__ Wto,
                                                     const float* __restrict__ bo,
                                                     float* __restrict__ out) {
    __shared__ __align__(16) bf16_t Ab[3][128 * 32];
    __shared__ __align__(16) bf16_t Bb[3][128 * 32];
    const int p = blockIdx.x;
    const int v0 = (p & 7) * 32 + (p >> 3);   // bijective: 256 = 8*32
    const int col0 = (v0 & 7) * 128;
    const int row0 = (v0 >> 3) * 128;
    const int tid = threadIdx.x, lane = tid & 63, w = tid >> 6;
    const int wr = w >> 1, wc = w & 1;
    const bf16_t* Asrc = AO + (size_t)row0 * D_;
    const bf16_t* Bsrc = Wto + (size_t)col0 * D_;

    f32x4 acc[4][4];
#pragma unroll
    for (int i = 0; i < 4; ++i)
#pragma unroll
        for (int j = 0; j < 4; ++j) acc[i][j] = (f32x4){0.f, 0.f, 0.f, 0.f};

    GEMM_KLOOP(Asrc, Bsrc)

#pragma unroll
    for (int i = 0; i < 4; ++i)
#pragma unroll
        for (int j = 0; j < 4; ++j)
#pragma unroll
            for (int r = 0; r < 4; ++r) {
                int grow = row0 + wr * 64 + i * 16 + 4 * (lane >> 4) + r;
                int gcol = col0 + wc * 64 + j * 16 + (lane & 15);
                out[(size_t)grow * D_ + gcol] = acc[i][j][r] + bo[gcol];
            }
}

// ---------- Flash attention v3: 4 waves x 32q, 32x32x16 MFMA, no-max softmax ----------
// LDS-byte amortization: one b128 A-frag feeds a 32x32x16 MFMA (16 FLOP/byte vs
// 8 for 16x16x32). Per wave-tile: 8 K-reads + 8 V-reads + 4 P-reads for 32 q
// (vs 18 reads for 16 q before) -> LDS read bytes ~halved.
// Swapped QK^T: D[k][q] = mfma(A=K[32k x 16d], B=Q[16d x 32q]); lane owns q col.
// PV: O^T[d][q] = mfma(A=V^T[32d x 16k], B=P^T[16k x 32q]).
// C/D layout (m74/m101): col=lane&31, row=(reg&3)+8*(reg>>2)+4*(lane>>5).
__global__ __launch_bounds__(256, 2) void k_attn(const bf16_t* __restrict__ Qh,
                                                 const bf16_t* __restrict__ Kh,
                                                 const bf16_t* __restrict__ Vt,
                                                 bf16_t* __restrict__ AO) {
    constexpr int NT = S_ / 64;
    __shared__ __align__(16) bf16_t Kb[2][64 * 64];
    __shared__ __align__(16) bf16_t Vb[2][64 * 64];
    __shared__ __align__(16) bf16_t Pt[4][32 * 64];   // per-wave P^T[32q][64k] / O staging
    const int tid = threadIdx.x, lane = tid & 63, w = tid >> 6;   // 4 waves
    const int q32 = lane & 31, hh = lane >> 5;   // lane's q-col and k/d-half
    const int bid = blockIdx.x;
    const int swz = (bid & 7) * 64 + (bid >> 3);  // XCD swizzle, 512 = 8*64
    const int qt = swz & 15, bh = swz >> 4;
    const int h = bh & 15, b = bh >> 4;
    const bf16_t* Qbase = Qh + ((size_t)bh * S_ + qt * 128 + w * 32) * HD_;
    const bf16_t* Kbase = Kh + (size_t)bh * S_ * HD_;
    const bf16_t* Vbase = Vt + (size_t)bh * HD_ * S_;
    char* PtC = (char*)Pt[w];

    // P^T/O wave-private [32 rows][64 cols] with 16B-slot swizzle: slot^=(row&7)
    auto psl = [&](int row, int slot, int sub) -> char* {
        return PtC + row * 128 + ((slot ^ (row & 7)) << 4) + sub;
    };

    // stage K [64 tok][64 d] and V^T [64 d][64 tok]; pre-swizzled source (swzb)
    auto stage = [&](int buf, int kt) {
#pragma unroll
        for (int c = 0; c < 2; ++c) {
            int idx = c * 256 + tid;
            int r = idx >> 3, s = idx & 7;
            int lsw = s ^ (r & 7);
            gl_lds16(Kbase + (size_t)(kt * 64 + r) * HD_ + lsw * 8, &Kb[buf][idx * 8]);
            gl_lds16(Vbase + (size_t)r * S_ + kt * 64 + lsw * 8, &Vb[buf][idx * 8]);
        }
    };

    // Q B-frags: lane owns col q32; d = ds*16 + 8*hh + e (8 consecutive)
    short8 qf[4];
#pragma unroll
    for (int ds = 0; ds < 4; ++ds)
        qf[ds] = *(const short8*)(Qbase + (size_t)q32 * HD_ + ds * 16 + 8 * hh);

    f32x4 ls4 = (f32x4){0.f, 0.f, 0.f, 0.f};
    f32x16 o0 = {}, o1 = {};   // O^T dblk 0 (d 0-31), 1 (d 32-63)

    stage(0, 0);
    __syncthreads();

#pragma unroll 2
    for (int kt = 0; kt < NT; ++kt) {
        const int cur = kt & 1;
        if (kt + 1 < NT) stage(cur ^ 1, kt + 1);   // prefetch flies under compute
        const char* KbC = (const char*)Kb[cur];
        const char* VbC = (const char*)Vb[cur];

        // ---- QK^T: s0 = S[k 0-31][q], s1 = S[k 32-63][q] ----
        f32x16 s0 = {}, s1 = {};
        __builtin_amdgcn_s_setprio(1);
#pragma unroll
        for (int ds = 0; ds < 4; ++ds) {
            const int cb = ds * 32 + 16 * hh;
            short8 k0 = *(const short8*)(KbC + swzb(q32, cb));
            short8 k1 = *(const short8*)(KbC + swzb(32 + q32, cb));
            s0 = __builtin_amdgcn_mfma_f32_32x32x16_bf16(k0, qf[ds], s0, 0, 0, 0);
            s1 = __builtin_amdgcn_mfma_f32_32x32x16_bf16(k1, qf[ds], s1, 0, 0, 0);
        }
        __builtin_amdgcn_s_setprio(0);

        // ---- no-max softmax: exp2 in place, 4-chain partial sums ----
#pragma unroll
        for (int r = 0; r < 16; ++r) {
            s0[r] = fast_exp2(s0[r]);
            s1[r] = fast_exp2(s1[r]);
        }
#pragma unroll
        for (int r = 0; r < 16; ++r) ls4[r & 3] += s0[r] + s1[r];

        // ---- P^T[q][k] pack -> wave-private LDS ----
        // reg quad j of s{t}: k = 8j + 4*hh + {0..3} + 32t -> slot j+4t, sub 8*hh
#pragma unroll
        for (int j = 0; j < 4; ++j) {
            short4 p0, p1;
            p0.x = f2bfs(s0[4 * j + 0]); p0.y = f2bfs(s0[4 * j + 1]);
            p0.z = f2bfs(s0[4 * j + 2]); p0.w = f2bfs(s0[4 * j + 3]);
            p1.x = f2bfs(s1[4 * j + 0]); p1.y = f2bfs(s1[4 * j + 1]);
            p1.z = f2bfs(s1[4 * j + 2]); p1.w = f2bfs(s1[4 * j + 3]);
            *(short4*)psl(q32, j, 8 * hh) = p0;
            *(short4*)psl(q32, j + 4, 8 * hh) = p1;
        }

        // ---- PV: o{dblk} += mfma(V^T[32d x 16k], P^T[16k x 32q]) ----
        __builtin_amdgcn_s_setprio(1);
#pragma unroll
        for (int ks = 0; ks < 4; ++ks) {
            short8 pv = *(const short8*)psl(q32, 2 * ks + hh, 0);
            const int cb = ks * 32 + 16 * hh;
            short8 v0 = *(const short8*)(VbC + swzb(q32, cb));
            short8 v1 = *(const short8*)(VbC + swzb(32 + q32, cb));
            o0 = __builtin_amdgcn_mfma_f32_32x32x16_bf16(v0, pv, o0, 0, 0, 0);
            o1 = __builtin_amdgcn_mfma_f32_32x32x16_bf16(v1, pv, o1, 0, 0, 0);
        }
        __builtin_amdgcn_s_setprio(0);
        __syncthreads();   // buf[cur] reads done + prefetch vmcnt drained
    }

    // ---- epilogue: lsum reduce (lanes q, q+32), normalize, transpose, store ----
    float lsum = (ls4[0] + ls4[1]) + (ls4[2] + ls4[3]);
    lsum += __shfl_xor(lsum, 32);
    float rls = __builtin_amdgcn_rcpf(lsum);
    // O[q][d] staged like P: d = 8j + 4*hh + {0..3} + 32*dblk -> slot j+4*dblk
#pragma unroll
    for (int j = 0; j < 4; ++j) {
        short4 w0, w1;
        w0.x = f2bfs(o0[4 * j + 0] * rls); w0.y = f2bfs(o0[4 * j + 1] * rls);
        w0.z = f2bfs(o0[4 * j + 2] * rls); w0.w = f2bfs(o0[4 * j + 3] * rls);
        w1.x = f2bfs(o1[4 * j + 0] * rls); w1.y = f2bfs(o1[4 * j + 1] * rls);
        w1.z = f2bfs(o1[4 * j + 2] * rls); w1.w = f2bfs(o1[4 * j + 3] * rls);
        *(short4*)psl(q32, j, 8 * hh) = w0;
        *(short4*)psl(q32, j + 4, 8 * hh) = w1;
    }
    // read rows coalesced: lane -> row r = lane>>1, d-half = (lane&1)*32
    const int r = lane >> 1;
    const int half = lane & 1;
    const int tok = qt * 128 + w * 32 + r;
    bf16_t* dst = AO + ((size_t)b * S_ + tok) * D_ + h * HD_ + half * 32;
#pragma unroll
    for (int c2 = 0; c2 < 4; ++c2) {
        short8 rr = *(const short8*)psl(r, half * 4 + c2, 0);
        *(short8*)(dst + c2 * 8) = rr;
    }
}

extern "C" void kernel_launch(void* const* d_in, const int* in_sizes, int n_in,
                              void* d_out, int out_size, void* d_ws, size_t ws_size,
                              hipStream_t stream) {
    const float* x  = (const float*)d_in[0];
    const float* Wq = (const float*)d_in[1];
    const float* bq = (const float*)d_in[2];
    const float* Wk = (const float*)d_in[3];
    const float* bk = (const float*)d_in[4];
    const float* Wv = (const float*)d_in[5];
    const float* bv = (const float*)d_in[6];
    const float* Wo = (const float*)d_in[7];
    const float* bo = (const float*)d_in[8];

    char* ws = (char*)d_ws;
    const size_t MB = 1024 * 1024;
    bf16_t* Wtq = (bf16_t*)(ws + 0 * MB);
    bf16_t* Wtk = (bf16_t*)(ws + 2 * MB);
    bf16_t* Wtv = (bf16_t*)(ws + 4 * MB);
    bf16_t* Wto = (bf16_t*)(ws + 6 * MB);
    bf16_t* xb  = (bf16_t*)(ws + 8 * MB);    // 8MB, dead after k_qkv
    bf16_t* Qh  = (bf16_t*)(ws + 16 * MB);   // [B,H,S,HD] (Q pre-scaled by SC2L)
    bf16_t* Kh  = (bf16_t*)(ws + 24 * MB);
    bf16_t* Vt  = (bf16_t*)(ws + 32 * MB);   // [B,H,HD,S]
    bf16_t* AO  = (bf16_t*)(ws + 8 * MB);    // reuses xb region

    k_prep<<<dim3(32, 32, 5), dim3(32, 8), 0, stream>>>(x, Wq, Wk, Wv, Wo, xb, Wtq, Wtk, Wtv, Wto);
    k_qkv<<<768, 256, 0, stream>>>(xb, Wtq, Wtk, Wtv, bq, bk, bv, Qh, Kh, Vt);
    k_attn<<<B_ * H_ * (S_ / 128), 256, 0, stream>>>(Qh, Kh, Vt, AO);
    k_gemm_out<<<256, 256, 0, stream>>>(AO, Wto, bo, (float*)d_out);
}

// Round 14
// 113.676 us; speedup vs baseline: 1.0293x; 1.0293x over previous
//
#include <hip/hip_runtime.h>
#include <hip/hip_bf16.h>

#define B_ 2
#define S_ 2048
#define D_ 1024
#define H_ 16
#define HD_ 64
#define M_ (B_ * S_)   // 4096 tokens

// scale folded into Q at projection time: exp(score/sqrt(HD)) = exp2(qk * SC2L)
#define SC2L 0.18033688011112042f   // 0.125 * log2(e)

typedef __attribute__((ext_vector_type(8))) short short8;
typedef __attribute__((ext_vector_type(4))) float f32x4;
using bf16_t = __hip_bfloat16;

__device__ __forceinline__ float fast_exp2(float x) { return __builtin_amdgcn_exp2f(x); }

__device__ __forceinline__ short f2bfs(float f) {
    __hip_bfloat16 h = __float2bfloat16(f);
    return *reinterpret_cast<short*>(&h);
}

typedef __attribute__((address_space(1))) const unsigned int gl_u32;
typedef __attribute__((address_space(3))) unsigned int lds_u32;

__device__ __forceinline__ void gl_lds16(const bf16_t* g, bf16_t* l) {
    __builtin_amdgcn_global_load_lds((gl_u32*)g, (lds_u32*)l, 16, 0, 0);
}

// XOR-swizzle for [R][64]-bf16 tiles (128 B rows), attn kernel.
__device__ __forceinline__ int swzb(int row, int colbyte) {
    return (row << 7) + (colbyte ^ ((row & 7) << 4));
}

// XOR-swizzle for [R][32]-bf16 tiles (64 B rows, 4 chunks of 16 B), GEMM BK=32.
__device__ __forceinline__ int swz32(int row, int chunk) {
    return (row << 6) + ((chunk ^ ((row >> 1) & 3)) << 4);
}

// ---------- fused prep: 4x W transpose->bf16 (z<4) + x->bf16 (z==4) ----------
__global__ __launch_bounds__(256) void k_prep(const float* __restrict__ x,
                                              const float* __restrict__ W0,
                                              const float* __restrict__ W1,
                                              const float* __restrict__ W2,
                                              const float* __restrict__ W3,
                                              bf16_t* __restrict__ xb,
                                              bf16_t* T0, bf16_t* T1, bf16_t* T2, bf16_t* T3) {
    const int z = blockIdx.z;
    const int tx = threadIdx.x, ty = threadIdx.y;           // (32, 8)
    if (z == 4) {
        const int blk = blockIdx.y * 32 + blockIdx.x;
        const int tid = ty * 32 + tx;
        int i = blk * 4096 + tid * 16;
#pragma unroll
        for (int half = 0; half < 2; ++half) {
            float4 f0 = ((const float4*)(x + i))[0];
            float4 f1 = ((const float4*)(x + i))[1];
            short8 v;
            v[0] = f2bfs(f0.x); v[1] = f2bfs(f0.y); v[2] = f2bfs(f0.z); v[3] = f2bfs(f0.w);
            v[4] = f2bfs(f1.x); v[5] = f2bfs(f1.y); v[6] = f2bfs(f1.z); v[7] = f2bfs(f1.w);
            *(short8*)(xb + i) = v;
            i += 8;
        }
        return;
    }
    __shared__ float tile[32][33];
    const float* W = z == 0 ? W0 : z == 1 ? W1 : z == 2 ? W2 : W3;
    bf16_t* Wt = z == 0 ? T0 : z == 1 ? T1 : z == 2 ? T2 : T3;
    const int n0 = blockIdx.x * 32, k0 = blockIdx.y * 32;
#pragma unroll
    for (int r = 0; r < 4; ++r)
        tile[ty + 8 * r][tx] = W[(size_t)(k0 + ty + 8 * r) * D_ + n0 + tx];
    __syncthreads();
#pragma unroll
    for (int r = 0; r < 4; ++r)
        Wt[(size_t)(n0 + ty + 8 * r) * D_ + k0 + tx] = __float2bfloat16(tile[tx][ty + 8 * r]);
}

// ---------- GEMM helpers: 128x128 tile, BK=32, 4 waves, 3-buf counted-vmcnt ----------
// Staging: pre-swizzled SOURCE + linear LDS dest; reads use swz32().
// Exactly 4 global_load_lds per thread per stage call (vmcnt accounting).
__device__ __forceinline__ void stage_pair32(const bf16_t* __restrict__ Asrc,
                                             const bf16_t* __restrict__ Bsrc,
                                             int k0, int tid,
                                             bf16_t* Ab, bf16_t* Bb) {
#pragma unroll
    for (int c = 0; c < 2; ++c) {
        int idx = c * 256 + tid;          // 0..511 chunk index over [128][4]
        int r = idx >> 2, ch = idx & 3;
        int cs = ch ^ ((r >> 1) & 3);     // pre-swizzled source chunk
        gl_lds16(Asrc + (size_t)r * D_ + k0 + cs * 8, Ab + idx * 8);
        gl_lds16(Bsrc + (size_t)r * D_ + k0 + cs * 8, Bb + idx * 8);
    }
}

__device__ __forceinline__ void gemm_compute32(const bf16_t* Ab, const bf16_t* Bb,
                                               int lane, int wr, int wc, f32x4 acc[4][4]) {
    const char* AbC = (const char*)Ab;
    const char* BbC = (const char*)Bb;
    const int g = lane >> 4;
    short8 af[4], bf[4];
    const int arow = wr * 64 + (lane & 15);
    const int brow = wc * 64 + (lane & 15);
#pragma unroll
    for (int i = 0; i < 4; ++i) af[i] = *(const short8*)(AbC + swz32(arow + i * 16, g));
#pragma unroll
    for (int j = 0; j < 4; ++j) bf[j] = *(const short8*)(BbC + swz32(brow + j * 16, g));
#pragma unroll
    for (int i = 0; i < 4; ++i)
#pragma unroll
        for (int j = 0; j < 4; ++j)
            acc[i][j] = __builtin_amdgcn_mfma_f32_16x16x32_bf16(af[i], bf[j], acc[i][j], 0, 0, 0);
}

// Counted-vmcnt depth-2 K-loop (T3/T4): stage(s+1) stays in flight ACROSS the
// barrier (vmcnt(4) waits only for stage(s)'s 4 loads); stage(s+2) is issued
// after the barrier (safe: all waves' step s-1 ds_reads retired at barrier).
#define GEMM_KLOOP(ASRC, BSRC)                                                   \
    stage_pair32(ASRC, BSRC, 0, tid, Ab[0], Bb[0]);                              \
    stage_pair32(ASRC, BSRC, 32, tid, Ab[1], Bb[1]);                             \
    constexpr int NS = D_ / 32;                                                  \
    _Pragma("unroll 3")                                                          \
    for (int step = 0; step < NS - 1; ++step) {                                  \
        asm volatile("s_waitcnt vmcnt(4)" ::: "memory");                         \
        __builtin_amdgcn_s_barrier();                                            \
        if (step + 2 < NS)                                                       \
            stage_pair32(ASRC, BSRC, (step + 2) * 32, tid,                       \
                         Ab[(step + 2) % 3], Bb[(step + 2) % 3]);                \
        gemm_compute32(Ab[step % 3], Bb[step % 3], lane, wr, wc, acc);           \
    }                                                                            \
    asm volatile("s_waitcnt vmcnt(0)" ::: "memory");                             \
    __builtin_amdgcn_s_barrier();                                                \
    gemm_compute32(Ab[(NS - 1) % 3], Bb[(NS - 1) % 3], lane, wr, wc, acc);

// ---------- fused QKV GEMM: Q (pre-scaled by SC2L), K -> [B,H,S,HD]; V -> [B,H,HD,S] ----------
__global__ __launch_bounds__(256, 4) void k_qkv(const bf16_t* __restrict__ xb,
                                                const bf16_t* __restrict__ Wtq,
                                                const bf16_t* __restrict__ Wtk,
                                                const bf16_t* __restrict__ Wtv,
                                                const float* __restrict__ bq,
                                                const float* __restrict__ bk,
                                                const float* __restrict__ bv,
                                                bf16_t* __restrict__ Qh,
                                                bf16_t* __restrict__ Kh,
                                                bf16_t* __restrict__ Vt) {
    __shared__ __align__(16) bf16_t Ab[3][128 * 32];
    __shared__ __align__(16) bf16_t Bb[3][128 * 32];
    const int p = blockIdx.x;
    const int v0 = (p & 7) * 96 + (p >> 3);   // bijective: 768 = 8*96
    const int sc = v0 % 24;
    const int sel = sc >> 3;
    const bf16_t* Bt = sel == 0 ? Wtq : sel == 1 ? Wtk : Wtv;
    const float* bias = sel == 0 ? bq : sel == 1 ? bk : bv;
    const int col0 = (sc & 7) * 128;
    const int row0 = (v0 / 24) * 128;
    const int tid = threadIdx.x, lane = tid & 63, w = tid >> 6;
    const int wr = w >> 1, wc = w & 1;
    const bf16_t* Asrc = xb + (size_t)row0 * D_;
    const bf16_t* Bsrc = Bt + (size_t)col0 * D_;

    f32x4 acc[4][4];
#pragma unroll
    for (int i = 0; i < 4; ++i)
#pragma unroll
        for (int j = 0; j < 4; ++j) acc[i][j] = (f32x4){0.f, 0.f, 0.f, 0.f};

    GEMM_KLOOP(Asrc, Bsrc)

#pragma unroll
    for (int i = 0; i < 4; ++i)
#pragma unroll
        for (int j = 0; j < 4; ++j)
#pragma unroll
            for (int r = 0; r < 4; ++r) {
                int grow = row0 + wr * 64 + i * 16 + 4 * (lane >> 4) + r;
                int gcol = col0 + wc * 64 + j * 16 + (lane & 15);
                float v = acc[i][j][r] + bias[gcol];
                int b = grow >> 11, s = grow & (S_ - 1);
                int h = gcol >> 6, hd = gcol & (HD_ - 1);
                if (sel == 0)   // fold softmax scale*log2(e) into Q (fp32, pre-round)
                    Qh[(((size_t)b * H_ + h) * S_ + s) * HD_ + hd] = __float2bfloat16(v * SC2L);
                else if (sel == 1)
                    Kh[(((size_t)b * H_ + h) * S_ + s) * HD_ + hd] = __float2bfloat16(v);
                else
                    Vt[(((size_t)b * H_ + h) * HD_ + hd) * S_ + s] = __float2bfloat16(v);
            }
}

// ---------- final projection: d_out[M,D] fp32 = AO[M,D]bf16 * Wto^T + bo ----------
__global__ __launch_bounds__(256, 4) void k_gemm_out(const bf16_t* __restrict__ AO,
                                                     const bf16_t* __restrict__ Wto,
                                                     const float* __restrict__ bo,
                                                     float* __restrict__ out) {
    __shared__ __align__(16) bf16_t Ab[3][128 * 32];
    __shared__ __align__(16) bf16_t Bb[3][128 * 32];
    const int p = blockIdx.x;
    const int v0 = (p & 7) * 32 + (p >> 3);   // bijective: 256 = 8*32
    const int col0 = (v0 & 7) * 128;
    const int row0 = (v0 >> 3) * 128;
    const int tid = threadIdx.x, lane = tid & 63, w = tid >> 6;
    const int wr = w >> 1, wc = w & 1;
    const bf16_t* Asrc = AO + (size_t)row0 * D_;
    const bf16_t* Bsrc = Wto + (size_t)col0 * D_;

    f32x4 acc[4][4];
#pragma unroll
    for (int i = 0; i < 4; ++i)
#pragma unroll
        for (int j = 0; j < 4; ++j) acc[i][j] = (f32x4){0.f, 0.f, 0.f, 0.f};

    GEMM_KLOOP(Asrc, Bsrc)

#pragma unroll
    for (int i = 0; i < 4; ++i)
#pragma unroll
        for (int j = 0; j < 4; ++j)
#pragma unroll
            for (int r = 0; r < 4; ++r) {
                int grow = row0 + wr * 64 + i * 16 + 4 * (lane >> 4) + r;
                int gcol = col0 + wc * 64 + j * 16 + (lane & 15);
                out[(size_t)grow * D_ + gcol] = acc[i][j][r] + bo[gcol];
            }
}

// ---------- Flash attention (proven form): 8 waves x 16q, no-max softmax ----------
// Swapped operands; Q pre-scaled so P = exp2(raw mfma out); 2-deep scA/scB
// pipeline with triple-buffered K/V; deferred lsum reduce in epilogue.
__global__ __launch_bounds__(512, 4) void k_attn(const bf16_t* __restrict__ Qh,
                                                 const bf16_t* __restrict__ Kh,
                                                 const bf16_t* __restrict__ Vt,
                                                 bf16_t* __restrict__ AO) {
    constexpr int NT = S_ / 64;
    __shared__ __align__(16) bf16_t Kb[3][64 * 64];
    __shared__ __align__(16) bf16_t Vb[3][64 * 64];
    __shared__ __align__(16) bf16_t Pt[8][16 * 64];   // per-wave P^T / O staging
    const int tid = threadIdx.x, lane = tid & 63, w = tid >> 6;
    const int g = lane >> 4, q = lane & 15;
    const int bid = blockIdx.x;
    const int swz = (bid & 7) * 64 + (bid >> 3);
    const int qt = swz & 15, bh = swz >> 4;
    const int h = bh & 15, b = bh >> 4;
    const bf16_t* Qbase = Qh + ((size_t)bh * S_ + qt * 128 + w * 16) * HD_;
    const bf16_t* Kbase = Kh + (size_t)bh * S_ * HD_;
    const bf16_t* Vbase = Vt + (size_t)bh * HD_ * S_;
    char* PtC = (char*)Pt[w];

    auto stage = [&](int buf, int kt) {
        int r = tid >> 3, s = tid & 7;
        int lsw = s ^ (r & 7);
        gl_lds16(Kbase + (size_t)(kt * 64 + r) * HD_ + lsw * 8, &Kb[buf][tid * 8]);
        gl_lds16(Vbase + (size_t)r * S_ + kt * 64 + lsw * 8, &Vb[buf][tid * 8]);
    };

    short8 qf[2];
#pragma unroll
    for (int kc = 0; kc < 2; ++kc)
        qf[kc] = *(const short8*)(Qbase + (size_t)q * HD_ + kc * 32 + 8 * g);

    f32x4 ls4 = (f32x4){0.f, 0.f, 0.f, 0.f};
    f32x4 o[4];
#pragma unroll
    for (int c = 0; c < 4; ++c) o[c] = (f32x4){0.f, 0.f, 0.f, 0.f};

    f32x4 scA[4], scB[4];

    auto qk_tile = [&](int kt, f32x4 (&sc)[4]) {
        const char* KbC = (const char*)Kb[kt % 3];
        __builtin_amdgcn_s_setprio(1);
#pragma unroll
        for (int ktb = 0; ktb < 4; ++ktb) {
            f32x4 a = (f32x4){0.f, 0.f, 0.f, 0.f};
#pragma unroll
            for (int kc = 0; kc < 2; ++kc) {
                short8 kf = *(const short8*)(KbC + swzb(ktb * 16 + q, kc * 64 + 16 * g));
                a = __builtin_amdgcn_mfma_f32_16x16x32_bf16(kf, qf[kc], a, 0, 0, 0);
            }
            sc[ktb] = a;
        }
        __builtin_amdgcn_s_setprio(0);
    };

    auto finish_pv = [&](f32x4 (&sc)[4], int vt) {
#pragma unroll
        for (int t = 0; t < 4; ++t)
#pragma unroll
            for (int r = 0; r < 4; ++r)
                sc[t][r] = fast_exp2(sc[t][r]);
        ls4 += (sc[0] + sc[1]) + (sc[2] + sc[3]);
#pragma unroll
        for (int t = 0; t < 4; ++t) {
            short4 pk;
            pk.x = f2bfs(sc[t][0]); pk.y = f2bfs(sc[t][1]);
            pk.z = f2bfs(sc[t][2]); pk.w = f2bfs(sc[t][3]);
            *(short4*)(PtC + swzb(q, t * 32 + 8 * g)) = pk;
        }
        const char* VbC = (const char*)Vb[vt % 3];
        __builtin_amdgcn_s_setprio(1);
#pragma unroll
        for (int kc = 0; kc < 2; ++kc) {
            short8 pf = *(const short8*)(PtC + swzb(q, kc * 64 + 16 * g));
#pragma unroll
            for (int c = 0; c < 4; ++c) {
                short8 vf = *(const short8*)(VbC + swzb(c * 16 + q, kc * 64 + 16 * g));
                o[c] = __builtin_amdgcn_mfma_f32_16x16x32_bf16(vf, pf, o[c], 0, 0, 0);
            }
        }
        __builtin_amdgcn_s_setprio(0);
    };

    stage(0, 0);
    __syncthreads();
    stage(1, 1);
    qk_tile(0, scA);

#pragma unroll 1
    for (int kt = 1; kt + 1 < NT; kt += 2) {
        __syncthreads();
        stage((kt + 1) % 3, kt + 1);
        qk_tile(kt, scB);
        finish_pv(scA, kt - 1);
        __syncthreads();
        if (kt + 2 < NT) stage((kt + 2) % 3, kt + 2);
        qk_tile(kt + 1, scA);
        finish_pv(scB, kt);
    }
    __syncthreads();
    qk_tile(NT - 1, scB);
    finish_pv(scA, NT - 2);
    finish_pv(scB, NT - 1);

    float lsum = (ls4[0] + ls4[1]) + (ls4[2] + ls4[3]);
    lsum += __shfl_xor(lsum, 16);
    lsum += __shfl_xor(lsum, 32);
    float rls = __builtin_amdgcn_rcpf(lsum);
#pragma unroll
    for (int c = 0; c < 4; ++c) {
        short4 ok;
        ok.x = f2bfs(o[c][0] * rls); ok.y = f2bfs(o[c][1] * rls);
        ok.z = f2bfs(o[c][2] * rls); ok.w = f2bfs(o[c][3] * rls);
        *(short4*)(PtC + swzb(q, c * 32 + 8 * g)) = ok;
    }
    const int tok = qt * 128 + w * 16 + (lane >> 2);
    const int dch = (lane & 3) * 32;
    short8 r0 = *(const short8*)(PtC + swzb(lane >> 2, dch));
    short8 r1 = *(const short8*)(PtC + swzb(lane >> 2, dch + 16));
    bf16_t* dst = AO + ((size_t)b * S_ + tok) * D_ + h * HD_ + (lane & 3) * 16;
    *(short8*)dst = r0;
    *(short8*)(dst + 8) = r1;
}

extern "C" void kernel_launch(void* const* d_in, const int* in_sizes, int n_in,
                              void* d_out, int out_size, void* d_ws, size_t ws_size,
                              hipStream_t stream) {
    const float* x  = (const float*)d_in[0];
    const float* Wq = (const float*)d_in[1];
    const float* bq = (const float*)d_in[2];
    const float* Wk = (const float*)d_in[3];
    const float* bk = (const float*)d_in[4];
    const float* Wv = (const float*)d_in[5];
    const float* bv = (const float*)d_in[6];
    const float* Wo = (const float*)d_in[7];
    const float* bo = (const float*)d_in[8];

    char* ws = (char*)d_ws;
    const size_t MB = 1024 * 1024;
    bf16_t* Wtq = (bf16_t*)(ws + 0 * MB);
    bf16_t* Wtk = (bf16_t*)(ws + 2 * MB);
    bf16_t* Wtv = (bf16_t*)(ws + 4 * MB);
    bf16_t* Wto = (bf16_t*)(ws + 6 * MB);
    bf16_t* xb  = (bf16_t*)(ws + 8 * MB);    // 8MB, dead after k_qkv
    bf16_t* Qh  = (bf16_t*)(ws + 16 * MB);   // [B,H,S,HD] (Q pre-scaled by SC2L)
    bf16_t* Kh  = (bf16_t*)(ws + 24 * MB);
    bf16_t* Vt  = (bf16_t*)(ws + 32 * MB);   // [B,H,HD,S]
    bf16_t* AO  = (bf16_t*)(ws + 8 * MB);    // reuses xb region

    k_prep<<<dim3(32, 32, 5), dim3(32, 8), 0, stream>>>(x, Wq, Wk, Wv, Wo, xb, Wtq, Wtk, Wtv, Wto);
    k_qkv<<<768, 256, 0, stream>>>(xb, Wtq, Wtk, Wtv, bq, bk, bv, Qh, Kh, Vt);
    k_attn<<<B_ * H_ * (S_ / 128), 512, 0, stream>>>(Qh, Kh, Vt, AO);
    k_gemm_out<<<256, 256, 0, stream>>>(AO, Wto, bo, (float*)d_out);
}